// Round 4
// baseline (2592.097 us; speedup 1.0000x reference)
//
#include <hip/hip_runtime.h>
#include <hip/hip_cooperative_groups.h>

namespace cg = cooperative_groups;

// SlotAttention, algebraically restructured:
//   logits = (LN(slots) @ (Wq^T @ Wk)) . x / 16   (q.bk term dropped: softmax-invariant)
//   updates = softmax-weighted-avg(x) @ Wv^T + bv  (attn rows sum to 1)
// R5/R6: k_attn wave-split pipeline — FLAT. R7: deep-prefetch 64-row subchunks — FLAT.
// Conclusion: per-kernel inner-loop structure is not the binding constraint; every
// dispatch is <157us (top-5 table cutoff) yet the 9-dispatch total is ~686us vs a
// ~220us bottom-up roofline. Suspect: inter-dispatch overhead / ramp / tail-drain.
// R8: ONE cooperative mega-kernel (grid 1024x256, 4 blocks/CU guaranteed:
//     LDS union 34.9KB, __launch_bounds__(256,4)) with grid.sync() between phases:
//     {wqk|conv} -> {init+qk0} -> 3x{attn -> upd}. k_upd/k_qk0 reworked to 256 thr
//     (4 tiles/wave); s1 eliminated via exact in-place aliasing (sp) and LN buffer
//     aliased onto cat cols [256,520). Launch-error fallback = benched R7 path.

constexpr int Bn = 64;    // batch
constexpr int Nn = 4096;  // inputs per batch
constexpr int Dd = 256;   // feature dim (== IN_D)
constexpr int Ss = 8;     // slots
constexpr int CH = 16;    // N-chunks per batch for attention
constexpr float EPSF = 1e-5f;

#define DEV __device__ __forceinline__

using short8 = __attribute__((ext_vector_type(8))) short;
using f32x4 = __attribute__((ext_vector_type(4))) float;
union U8 { short8 s; uint4 u; };

DEV unsigned bfpack2(float lo, float hi) {
  unsigned ul = __float_as_uint(lo), uh = __float_as_uint(hi);
  ul = (ul + 0x7FFFu + ((ul >> 16) & 1u)) >> 16;         // RNE to bf16
  uh = (uh + 0x7FFFu + ((uh >> 16) & 1u)) & 0xFFFF0000u;
  return ul | uh;
}
DEV unsigned short bf16r(float x) {
  unsigned u = __float_as_uint(x);
  u = (u + 0x7FFFu + ((u >> 16) & 1u)) >> 16;
  return (unsigned short)u;
}
DEV float rsum32(float v) {  // sum within each 32-lane half of a wave
  v += __shfl_xor(v, 1); v += __shfl_xor(v, 2); v += __shfl_xor(v, 4);
  v += __shfl_xor(v, 8); v += __shfl_xor(v, 16);
  return v;
}
DEV float sigm(float x) { return 1.f / (1.f + __expf(-x)); }

// ---- MFMA tile helpers: C[row=quad*4+r][col=t*16+m16] = sum_k A[row][k] W[col][k] + b
template <int NK>
DEV void load_af(short8* a, const unsigned short* base, int lda, int m16, int quad) {
  const unsigned short* p = base + m16 * lda + quad * 8;
#pragma unroll
  for (int kk = 0; kk < NK; ++kk) a[kk] = *(const short8*)(p + kk * 32);
}
template <int NK>
DEV f32x4 gemm_tile(const short8* a, const unsigned short* wr, float binit) {
  f32x4 acc = {binit, binit, binit, binit};
#pragma unroll
  for (int kk = 0; kk < NK; ++kk) {
    short8 b = *(const short8*)(wr + kk * 32);
    acc = __builtin_amdgcn_mfma_f32_16x16x32_bf16(a[kk], b, acc, 0, 0, 0);
  }
  return acc;
}

// LayerNorm over one 256-row held 8-per-thread by 32 lanes; writes bf16 packed out.
DEV void ln_row8(const float* x, const float* g, const float* b, int d0,
                 unsigned short* dst) {
  float s = x[0] + x[1] + x[2] + x[3] + x[4] + x[5] + x[6] + x[7];
  float mu = rsum32(s) * (1.f / 256.f);
  float q = 0.f;
#pragma unroll
  for (int j = 0; j < 8; ++j) { float d = x[j] - mu; q += d * d; }
  float rs = rsqrtf(rsum32(q) * (1.f / 256.f) + EPSF);
  float o[8];
#pragma unroll
  for (int j = 0; j < 8; ++j) o[j] = (x[j] - mu) * rs * g[d0 + j] + b[d0 + j];
  uint4 w;
  w.x = bfpack2(o[0], o[1]); w.y = bfpack2(o[2], o[3]);
  w.z = bfpack2(o[4], o[5]); w.w = bfpack2(o[6], o[7]);
  *(uint4*)dst = w;
}

// ================= shared device bodies =================

// ---- attention unit (one (b,c) tile; 256 threads' worth of work) ----
template <bool FIRST>
DEV void ld_chunk_t(const float* __restrict__ xin, unsigned* __restrict__ xbf,
                    size_t nbase, int tid, uint4* pr) {
#pragma unroll
  for (int i = 0; i < 8; ++i) {
    int flat = i * 256 + tid, n = flat >> 5, od = flat & 31;
    if (FIRST) {
      const float4* src = (const float4*)(xin + (nbase + n) * 256 + od * 8);
      float4 v0 = src[0], v1 = src[1];
      uint4 o;
      o.x = bfpack2(v0.x, v0.y); o.y = bfpack2(v0.z, v0.w);
      o.z = bfpack2(v1.x, v1.y); o.w = bfpack2(v1.z, v1.w);
      ((uint4*)xbf)[(nbase + n) * 32 + od] = o;
      pr[i] = o;
    } else {
      pr[i] = ((const uint4*)xbf)[(nbase + n) * 32 + od];
    }
  }
}
DEV void ld_chunk_rt(bool first, const float* __restrict__ xin,
                     unsigned* __restrict__ xbf, size_t nbase, int tid, uint4* pr) {
  if (first) ld_chunk_t<true>(xin, xbf, nbase, tid, pr);
  else ld_chunk_t<false>(xin, xbf, nbase, tid, pr);
}

DEV void attn_unit(const float* __restrict__ xin, unsigned* __restrict__ xbf,
                   const float* __restrict__ qk, float* __restrict__ pl,
                   float* __restrict__ pu, unsigned* xt, unsigned* pp,
                   float (*lred)[16], int u, bool first, int tid) {
  const int lane = tid & 63, wave = tid >> 6;
  const int m16 = lane & 15, quad = lane >> 4;
  const int b = u >> 4, c = u & 15;
  const int pb = u * 8;
  const unsigned psel = (m16 & 1) ? 0x07060302u : 0x05040100u;

  short8 aq[8];
  {
    const float* qrow = qk + (size_t)(b * 8 + (m16 & 7)) * 256 + quad * 8;
#pragma unroll
    for (int kk = 0; kk < 8; ++kk) {
      U8 f;
      float4 q0 = *(const float4*)(qrow + kk * 32);
      float4 q1 = *(const float4*)(qrow + kk * 32 + 4);
      f.u.x = bfpack2(q0.x, q0.y); f.u.y = bfpack2(q0.z, q0.w);
      f.u.z = bfpack2(q1.x, q1.y); f.u.w = bfpack2(q1.z, q1.w);
      if (m16 >= 8) { f.u.x = 0u; f.u.y = 0u; f.u.z = 0u; f.u.w = 0u; }
      aq[kk] = f.s;
    }
  }
  float lacc[4] = {0.f, 0.f, 0.f, 0.f};
  f32x4 acc[4];
#pragma unroll
  for (int t = 0; t < 4; ++t) acc[t] = (f32x4){0.f, 0.f, 0.f, 0.f};
  const int d0w = wave * 64;

  uint4 pr[8];
  const size_t nb0 = (size_t)b * Nn + (size_t)c * 256;
  ld_chunk_rt(first, xin, xbf, nb0, tid, pr);

  for (int ch = 0; ch < 4; ++ch) {
#pragma unroll
    for (int i = 0; i < 8; ++i) {
      int flat = i * 256 + tid, n = flat >> 5, od = flat & 31, rb = od * 4;
      xt[(rb + 0) * 65 + n] = pr[i].x;
      xt[(rb + 1) * 65 + n] = pr[i].y;
      xt[(rb + 2) * 65 + n] = pr[i].z;
      xt[(rb + 3) * 65 + n] = pr[i].w;
    }
    __syncthreads();
    if (ch + 1 < 4)
      ld_chunk_rt(first, xin, xbf, nb0 + (size_t)(ch + 1) * 64, tid, pr);
    // phase A: wave w computes n-tile nt=w
    {
      const int nt = wave;
      f32x4 pacc = (f32x4){0.f, 0.f, 0.f, 0.f};
#pragma unroll
      for (int kk = 0; kk < 8; ++kk) {
        int base = (kk * 16 + quad * 4) * 65 + nt * 16 + m16;
        U8 bf;
        bf.u.x = xt[base]; bf.u.y = xt[base + 65];
        bf.u.z = xt[base + 130]; bf.u.w = xt[base + 195];
        pacc = __builtin_amdgcn_mfma_f32_16x16x32_bf16(aq[kk], bf.s, pacc, 0, 0, 0);
      }
      const int xrow = nt * 16 + m16;
      unsigned short* pps = (unsigned short*)pp;
#pragma unroll
      for (int r = 0; r < 4; ++r) {
        float p = __expf(pacc[r]);  // |logit| small: no max-shift needed
        lacc[r] += p;
        pps[((xrow >> 1) * 17 + quad * 4 + r) * 2 + (xrow & 1)] = bf16r(p);
      }
    }
    __syncthreads();
    // phase B: wave owns 64 d-cols
#pragma unroll
    for (int nh = 0; nh < 2; ++nh) {
      U8 bp;
      bp.u.x = pp[(nh * 16 + quad * 4 + 0) * 17 + m16];
      bp.u.y = pp[(nh * 16 + quad * 4 + 1) * 17 + m16];
      bp.u.z = pp[(nh * 16 + quad * 4 + 2) * 17 + m16];
      bp.u.w = pp[(nh * 16 + quad * 4 + 3) * 17 + m16];
#pragma unroll
      for (int t = 0; t < 4; ++t) {
        int d = d0w + t * 16 + m16;
        const unsigned* xr = xt + (d >> 1) * 65 + nh * 32 + quad * 8;
        unsigned u0 = xr[0], u1 = xr[1], u2 = xr[2], u3 = xr[3];
        unsigned u4 = xr[4], u5 = xr[5], u6 = xr[6], u7 = xr[7];
        U8 af;
        af.u.x = __builtin_amdgcn_perm(u1, u0, psel);
        af.u.y = __builtin_amdgcn_perm(u3, u2, psel);
        af.u.z = __builtin_amdgcn_perm(u5, u4, psel);
        af.u.w = __builtin_amdgcn_perm(u7, u6, psel);
        acc[t] = __builtin_amdgcn_mfma_f32_16x16x32_bf16(af.s, bp.s, acc[t], 0, 0, 0);
      }
    }
    __syncthreads();
  }
  if (m16 < 8) {
#pragma unroll
    for (int t = 0; t < 4; ++t)
#pragma unroll
      for (int r = 0; r < 4; ++r)
        pu[(size_t)(pb + m16) * 256 + d0w + t * 16 + quad * 4 + r] = acc[t][r];
  }
#pragma unroll
  for (int r = 0; r < 4; ++r) {
    float v = lacc[r];
    v += __shfl_xor(v, 1); v += __shfl_xor(v, 2);
    v += __shfl_xor(v, 4); v += __shfl_xor(v, 8);
    if (m16 == 0) lred[wave][quad * 4 + r] = v;
  }
  __syncthreads();
  if (tid < 8)
    pl[pb + tid] = lred[0][tid] + lred[1][tid] + lred[2][tid] + lred[3][tid];
}

// ---- 256-thread slot-update body (mega): 16 rows, 4 tiles/wave, s1 in-place in sp,
//      LN buffer aliased onto cat cols [256,520) ----
DEV void upd_body256(
    const float* __restrict__ pl, const float* __restrict__ pu,
    const unsigned short* __restrict__ Wv_b, const float* __restrict__ bv,
    const unsigned short* __restrict__ Wzr_b, const float* __restrict__ bzr,
    const unsigned short* __restrict__ Win_b, const float* __restrict__ bin,
    const unsigned short* __restrict__ Whn_b, const float* __restrict__ bhn,
    const unsigned short* __restrict__ W1_b, const float* __restrict__ b1,
    const unsigned short* __restrict__ W2_b, const float* __restrict__ b2,
    const float* __restrict__ gml, const float* __restrict__ bml,
    const float* __restrict__ gsl, const float* __restrict__ bsl,
    const unsigned short* __restrict__ Wqk_b, const float* __restrict__ bqk,
    float* __restrict__ slots, float* __restrict__ qk, float* __restrict__ dout,
    unsigned short* cat, float* sp, int bb, int tid) {
  unsigned short* lnbp = cat + 256;  // per-row cols [256,520), stride 520
  const int lane = tid & 63, wave4 = tid >> 6;
  const int m16 = lane & 15, quad = lane >> 4;
  const int row8 = tid >> 5, l32 = tid & 31, d0 = l32 * 8;
  // step 1: combine
#pragma unroll
  for (int r2 = 0; r2 < 2; ++r2) {
    const int row = row8 + 8 * r2;
    const int bat = 2 * bb + (row >> 3), sl = row & 7;
    float L = 0.f;
#pragma unroll
    for (int cc = 0; cc < 16; ++cc) L += pl[(bat * 16 + cc) * 8 + sl];
    float li = 1.f / L;
    float a[8] = {0.f, 0.f, 0.f, 0.f, 0.f, 0.f, 0.f, 0.f};
    for (int cc = 0; cc < 16; ++cc) {
      const float* pp_ = pu + ((size_t)(bat * 16 + cc) * 8 + sl) * 256 + d0;
      float4 v0 = *(const float4*)pp_, v1 = *(const float4*)(pp_ + 4);
      a[0] += v0.x; a[1] += v0.y; a[2] += v0.z; a[3] += v0.w;
      a[4] += v1.x; a[5] += v1.y; a[6] += v1.z; a[7] += v1.w;
    }
    uint4 o;
    o.x = bfpack2(a[0] * li, a[1] * li); o.y = bfpack2(a[2] * li, a[3] * li);
    o.z = bfpack2(a[4] * li, a[5] * li); o.w = bfpack2(a[6] * li, a[7] * li);
    *(uint4*)(cat + row * 520 + d0) = o;
    const float* sp_ = slots + (size_t)(bb * 16 + row) * 256 + d0;
    float4 h0 = *(const float4*)sp_, h1 = *(const float4*)(sp_ + 4);
    *(float4*)(sp + row * 260 + d0) = h0;
    *(float4*)(sp + row * 260 + d0 + 4) = h1;
    uint4 hb;
    hb.x = bfpack2(h0.x, h0.y); hb.y = bfpack2(h0.z, h0.w);
    hb.z = bfpack2(h1.x, h1.y); hb.w = bfpack2(h1.z, h1.w);
    *(uint4*)(cat + row * 520 + 256 + d0) = hb;
  }
  __syncthreads();
  // step 2: updates = u' @ Wv^T + bv
  short8 afr[16];
  load_af<8>(afr, cat, 520, m16, quad);
  f32x4 accv[4];
#pragma unroll
  for (int i = 0; i < 4; ++i) {
    int t = wave4 + 4 * i;
    accv[i] = gemm_tile<8>(afr, Wv_b + (size_t)(t * 16 + m16) * 256 + quad * 8,
                           bv[t * 16 + m16]);
  }
  __syncthreads();
#pragma unroll
  for (int i = 0; i < 4; ++i) {
    int t = wave4 + 4 * i;
#pragma unroll
    for (int r = 0; r < 4; ++r)
      cat[(quad * 4 + r) * 520 + t * 16 + m16] = bf16r(accv[i][r]);
  }
  __syncthreads();
  // steps 3+4 merged per-tile: gates transient, slots1 written in-place into sp
  load_af<16>(afr, cat, 520, m16, quad);
#pragma unroll
  for (int i = 0; i < 4; ++i) {
    int t = wave4 + 4 * i, col = t * 16 + m16;
    f32x4 ar = gemm_tile<16>(afr, Wzr_b + (size_t)(t * 16 + m16) * 512 + quad * 8,
                             bzr[t * 16 + m16]);
    f32x4 az = gemm_tile<16>(afr, Wzr_b + (size_t)((t + 16) * 16 + m16) * 512 + quad * 8,
                             bzr[(t + 16) * 16 + m16]);
    f32x4 ain = gemm_tile<8>(afr, Win_b + (size_t)(t * 16 + m16) * 256 + quad * 8,
                             bin[col]);
    f32x4 ahn = gemm_tile<8>(afr + 8, Whn_b + (size_t)(t * 16 + m16) * 256 + quad * 8,
                             bhn[col]);
#pragma unroll
    for (int r = 0; r < 4; ++r) {
      int rw = quad * 4 + r;
      float rrv = sigm(ar[r]), zzv = sigm(az[r]);
      float nin = ain[r] + rrv * ahn[r];
      float nn = 1.f - 2.f / (__expf(2.f * nin) + 1.f);  // tanh
      float hpc = sp[rw * 260 + col];
      sp[rw * 260 + col] = hpc + (1.f - zzv) * nn + zzv * hpc;  // prev + h_new
    }
  }
  __syncthreads();
  // step 5: LN_mlp(slots1) -> lnbp
#pragma unroll
  for (int r2 = 0; r2 < 2; ++r2) {
    int row = row8 + 8 * r2;
    const float* s1r = sp + row * 260 + d0;
    float4 v0 = *(const float4*)s1r, v1 = *(const float4*)(s1r + 4);
    float x[8] = {v0.x, v0.y, v0.z, v0.w, v1.x, v1.y, v1.z, v1.w};
    ln_row8(x, gml, bml, d0, lnbp + row * 520 + d0);
  }
  __syncthreads();
  // step 6: hid = relu(LN_mlp @ W1^T + b1) -> cat[:,0:256)
  load_af<8>(afr, lnbp, 520, m16, quad);
#pragma unroll
  for (int i = 0; i < 4; ++i) {
    int t = wave4 + 4 * i;
    f32x4 acc = gemm_tile<8>(afr, W1_b + (size_t)(t * 16 + m16) * 256 + quad * 8,
                             b1[t * 16 + m16]);
#pragma unroll
    for (int r = 0; r < 4; ++r)
      cat[(quad * 4 + r) * 520 + t * 16 + m16] = bf16r(fmaxf(acc[r], 0.f));
  }
  __syncthreads();
  // step 7: slots2 = slots1 + hid @ W2^T + b2 (in-place into sp) + global
  load_af<8>(afr, cat, 520, m16, quad);
#pragma unroll
  for (int i = 0; i < 4; ++i) {
    int t = wave4 + 4 * i;
    f32x4 acc = gemm_tile<8>(afr, W2_b + (size_t)(t * 16 + m16) * 256 + quad * 8,
                             b2[t * 16 + m16]);
#pragma unroll
    for (int r = 0; r < 4; ++r) {
      int rw = quad * 4 + r, col = t * 16 + m16;
      float v = acc[r] + sp[rw * 260 + col];
      size_t gi = (size_t)(bb * 16 + rw) * 256 + col;
      slots[gi] = v;
      if (dout) dout[gi] = v;
      sp[rw * 260 + col] = v;
    }
  }
  __syncthreads();
  // step 8: LN_slots(slots2) -> lnbp
#pragma unroll
  for (int r2 = 0; r2 < 2; ++r2) {
    int row = row8 + 8 * r2;
    const float* spr = sp + row * 260 + d0;
    float4 v0 = *(const float4*)spr, v1 = *(const float4*)(spr + 4);
    float x[8] = {v0.x, v0.y, v0.z, v0.w, v1.x, v1.y, v1.z, v1.w};
    ln_row8(x, gsl, bsl, d0, lnbp + row * 520 + d0);
  }
  __syncthreads();
  // step 9: q' = (LN_slots @ WqkT + bqk)/16
  load_af<8>(afr, lnbp, 520, m16, quad);
#pragma unroll
  for (int i = 0; i < 4; ++i) {
    int t = wave4 + 4 * i;
    f32x4 acc = gemm_tile<8>(afr, Wqk_b + (size_t)(t * 16 + m16) * 256 + quad * 8,
                             bqk[t * 16 + m16]);
#pragma unroll
    for (int r = 0; r < 4; ++r)
      qk[(size_t)(bb * 16 + quad * 4 + r) * 256 + t * 16 + m16] = acc[r] * 0.0625f;
  }
}

// ---- 256-thread init+qk0 body (mega): 16 rows/block, LN into cat-aliased lnbp ----
DEV void qk0_body256(const float* __restrict__ noise, const float* __restrict__ s_mu,
                     const float* __restrict__ s_sg, const float* __restrict__ gsl,
                     const float* __restrict__ bsl,
                     const unsigned short* __restrict__ Wqk_b,
                     const float* __restrict__ bqk, float* __restrict__ slots,
                     float* __restrict__ qk, unsigned short* cat, int bb, int tid) {
  unsigned short* lnbp = cat + 256;
  const int lane = tid & 63, wave4 = tid >> 6;
  const int m16 = lane & 15, quad = lane >> 4;
  const int row8 = tid >> 5, l32 = tid & 31, d0 = l32 * 8;
#pragma unroll
  for (int r2 = 0; r2 < 2; ++r2) {
    const int row = row8 + 8 * r2;
    const int grow = bb * 16 + row;
    const int sidx = (grow & 7) * 256 + d0;
    const float* np = noise + (size_t)grow * 256 + d0;
    float4 n0 = *(const float4*)np, n1 = *(const float4*)(np + 4);
    float4 m0 = *(const float4*)(s_mu + sidx), m1 = *(const float4*)(s_mu + sidx + 4);
    float4 g0 = *(const float4*)(s_sg + sidx), g1 = *(const float4*)(s_sg + sidx + 4);
    float x[8] = {m0.x + g0.x * n0.x, m0.y + g0.y * n0.y,
                  m0.z + g0.z * n0.z, m0.w + g0.w * n0.w,
                  m1.x + g1.x * n1.x, m1.y + g1.y * n1.y,
                  m1.z + g1.z * n1.z, m1.w + g1.w * n1.w};
    float* sp_ = slots + (size_t)grow * 256 + d0;
    float4 o0, o1;
    o0.x = x[0]; o0.y = x[1]; o0.z = x[2]; o0.w = x[3];
    o1.x = x[4]; o1.y = x[5]; o1.z = x[6]; o1.w = x[7];
    *(float4*)sp_ = o0; *(float4*)(sp_ + 4) = o1;
    ln_row8(x, gsl, bsl, d0, lnbp + row * 520 + d0);
  }
  __syncthreads();
  short8 a8[8];
  load_af<8>(a8, lnbp, 520, m16, quad);
#pragma unroll
  for (int i = 0; i < 4; ++i) {
    int t = wave4 + 4 * i;
    f32x4 acc = gemm_tile<8>(a8, Wqk_b + (size_t)(t * 16 + m16) * 256 + quad * 8,
                             bqk[t * 16 + m16]);
#pragma unroll
    for (int r = 0; r < 4; ++r)
      qk[(size_t)(bb * 16 + quad * 4 + r) * 256 + t * 16 + m16] = acc[r] * 0.0625f;
  }
}

// ---- prep unit: u<256 wqk col; u==256 bqk; u>=257 conv chunks ----
DEV void prep_unit(int u, int tid,
                   const float* Wq, const float* Wk, const float* bq,
                   unsigned short* Wqk_b, float* bqk,
                   const float* Wv, const float* Wih, const float* Whh,
                   const float* W1, const float* W2,
                   const float* bih, const float* bhh,
                   unsigned* Wv_b, unsigned* Wzr_b, unsigned* Win_b, unsigned* Whn_b,
                   unsigned* W1_b, unsigned* W2_b, float* bzr) {
  if (u < 256) {
    float acc = 0.f;
    for (int e = 0; e < 256; ++e) acc += Wq[e * 256 + tid] * Wk[e * 256 + u];
    Wqk_b[u * 256 + tid] = bf16r(acc);
  } else if (u == 256) {
    float acc = 0.f;
    for (int e = 0; e < 256; ++e) acc += bq[e] * Wk[e * 256 + tid];
    bqk[tid] = acc;
  } else {
    int cu = u - 257;
    if (cu >= 1152) {
      int i = (cu - 1152) * 256 + tid;
      if (i < 512) bzr[i] = bih[i] + bhh[i];
      return;
    }
    int p = cu * 256 + tid;
    const float* src; unsigned* dst;
    if (p < 32768) { src = Wv + 2 * p; dst = Wv_b + p; }
    else if (p < 163840) {
      int q = p - 32768, row = q >> 8, col = (q & 255) * 2;
      src = (col < 256) ? (Wih + row * 256 + col) : (Whh + row * 256 + col - 256);
      dst = Wzr_b + q;
    }
    else if (p < 196608) { int q = p - 163840; src = Wih + 512 * 256 + 2 * q; dst = Win_b + q; }
    else if (p < 229376) { int q = p - 196608; src = Whh + 512 * 256 + 2 * q; dst = Whn_b + q; }
    else if (p < 262144) { int q = p - 229376; src = W1 + 2 * q; dst = W1_b + q; }
    else { int q = p - 262144; src = W2 + 2 * q; dst = W2_b + q; }
    dst[0] = bfpack2(src[0], src[1]);
  }
}

// ================= mega cooperative kernel =================
struct MegaArgs {
  const float *inputs, *noise, *s_mu, *s_sg;
  const float *Wq, *bq, *Wk, *Wv, *bv, *Wih, *bih, *Whh, *bhh;
  const float *W1, *b1, *W2, *b2, *gsl, *bsl, *gml, *bml;
  unsigned* xbf;
  float *slots, *qk, *bqk, *pl, *pu, *bzr;
  unsigned short *Wv_b, *Wzr_b, *Win_b, *Whn_b, *W1_b, *W2_b, *Wqk_b;
  float* out;
};

__global__ __launch_bounds__(256, 4) void k_mega(MegaArgs a) {
  __shared__ __align__(16) union SMU {
    struct { unsigned xt[128 * 65]; unsigned pp[32 * 17]; float lred[4][16]; } at;
    struct { unsigned short cat[16 * 520]; float sp[16 * 260]; } up;
  } sm;
  const int tid = threadIdx.x, bid = blockIdx.x;
  cg::grid_group grid = cg::this_grid();
  // P0: wqk + conv
  for (int u = bid; u < 1411; u += (int)gridDim.x)
    prep_unit(u, tid, a.Wq, a.Wk, a.bq, a.Wqk_b, a.bqk, a.Wv, a.Wih, a.Whh, a.W1,
              a.W2, a.bih, a.bhh, (unsigned*)a.Wv_b, (unsigned*)a.Wzr_b,
              (unsigned*)a.Win_b, (unsigned*)a.Whn_b, (unsigned*)a.W1_b,
              (unsigned*)a.W2_b, a.bzr);
  __threadfence();
  grid.sync();
  // P1: init slots + q0
  if (bid < 32)
    qk0_body256(a.noise, a.s_mu, a.s_sg, a.gsl, a.bsl, a.Wqk_b, a.bqk, a.slots, a.qk,
                sm.up.cat, bid, tid);
  __threadfence();
  grid.sync();
  for (int it = 0; it < 3; ++it) {
    attn_unit(a.inputs, a.xbf, a.qk, a.pl, a.pu, sm.at.xt, sm.at.pp, sm.at.lred,
              bid, it == 0, tid);
    __threadfence();
    grid.sync();
    if (bid < 32)
      upd_body256(a.pl, a.pu, a.Wv_b, a.bv, a.Wzr_b, a.bzr, a.Win_b, a.bih + 512,
                  a.Whn_b, a.bhh + 512, a.W1_b, a.b1, a.W2_b, a.b2, a.gml, a.bml,
                  a.gsl, a.bsl, a.Wqk_b, a.bqk, a.slots, a.qk,
                  (it == 2) ? a.out : nullptr, sm.up.cat, sm.up.sp, bid, tid);
    __threadfence();
    grid.sync();
  }
}

// ================= legacy fallback kernels (benched R7 path) =================
__global__ __launch_bounds__(256) void k_wqk(const float* __restrict__ Wq,
                                             const float* __restrict__ Wk,
                                             const float* __restrict__ bq,
                                             unsigned short* __restrict__ Wqk_b,
                                             float* __restrict__ bqk) {
  int tid = threadIdx.x, c = blockIdx.x;
  if (c < 256) {
    float acc = 0.f;
    for (int e = 0; e < 256; ++e) acc += Wq[e * 256 + tid] * Wk[e * 256 + c];
    Wqk_b[c * 256 + tid] = bf16r(acc);
  } else {
    float acc = 0.f;
    for (int e = 0; e < 256; ++e) acc += bq[e] * Wk[e * 256 + tid];
    bqk[tid] = acc;
  }
}

__global__ __launch_bounds__(256) void k_conv(
    const float* __restrict__ Wv, const float* __restrict__ Wih,
    const float* __restrict__ Whh, const float* __restrict__ W1,
    const float* __restrict__ W2,
    const float* __restrict__ bih, const float* __restrict__ bhh,
    unsigned* Wv_b, unsigned* Wzr_b, unsigned* Win_b, unsigned* Whn_b,
    unsigned* W1_b, unsigned* W2_b, float* bzr) {
  if (blockIdx.x >= 1152) {
    int i = (blockIdx.x - 1152) * 256 + threadIdx.x;
    if (i < 512) bzr[i] = bih[i] + bhh[i];
    return;
  }
  int p = blockIdx.x * 256 + threadIdx.x;
  const float* src; unsigned* dst;
  if (p < 32768) { src = Wv + 2 * p; dst = Wv_b + p; }
  else if (p < 163840) {
    int q = p - 32768, row = q >> 8, col = (q & 255) * 2;
    src = (col < 256) ? (Wih + row * 256 + col) : (Whh + row * 256 + col - 256);
    dst = Wzr_b + q;
  }
  else if (p < 196608) { int q = p - 163840; src = Wih + 512 * 256 + 2 * q; dst = Win_b + q; }
  else if (p < 229376) { int q = p - 196608; src = Whh + 512 * 256 + 2 * q; dst = Whn_b + q; }
  else if (p < 262144) { int q = p - 229376; src = W1 + 2 * q; dst = W1_b + q; }
  else { int q = p - 262144; src = W2 + 2 * q; dst = W2_b + q; }
  dst[0] = bfpack2(src[0], src[1]);
}

__global__ __launch_bounds__(512) void k_qk0(const float* __restrict__ noise,
                                             const float* __restrict__ s_mu,
                                             const float* __restrict__ s_sg,
                                             const float* __restrict__ gsl,
                                             const float* __restrict__ bsl,
                                             const unsigned short* __restrict__ Wqk_b,
                                             const float* __restrict__ bqk,
                                             float* __restrict__ slots,
                                             float* __restrict__ qk) {
  __shared__ __align__(16) unsigned short lnb[16 * 264];
  const int tid = threadIdx.x, bb = blockIdx.x;
  const int lane = tid & 63, wave = tid >> 6;
  const int m16 = lane & 15, quad = lane >> 4;
  const int row = tid >> 5, l32 = tid & 31, d0 = l32 * 8;
  {
    const int grow = bb * 16 + row;
    const int sidx = (grow & 7) * 256 + d0;
    const float* np = noise + (size_t)grow * 256 + d0;
    float4 n0 = *(const float4*)np, n1 = *(const float4*)(np + 4);
    float4 m0 = *(const float4*)(s_mu + sidx), m1 = *(const float4*)(s_mu + sidx + 4);
    float4 g0 = *(const float4*)(s_sg + sidx), g1 = *(const float4*)(s_sg + sidx + 4);
    float x[8] = {m0.x + g0.x * n0.x, m0.y + g0.y * n0.y,
                  m0.z + g0.z * n0.z, m0.w + g0.w * n0.w,
                  m1.x + g1.x * n1.x, m1.y + g1.y * n1.y,
                  m1.z + g1.z * n1.z, m1.w + g1.w * n1.w};
    float* sp_ = slots + (size_t)grow * 256 + d0;
    float4 o0, o1;
    o0.x = x[0]; o0.y = x[1]; o0.z = x[2]; o0.w = x[3];
    o1.x = x[4]; o1.y = x[5]; o1.z = x[6]; o1.w = x[7];
    *(float4*)sp_ = o0; *(float4*)(sp_ + 4) = o1;
    ln_row8(x, gsl, bsl, d0, lnb + row * 264 + d0);
  }
  __syncthreads();
  short8 a8[8];
  load_af<8>(a8, lnb, 264, m16, quad);
#pragma unroll
  for (int i = 0; i < 2; ++i) {
    int t = wave + 8 * i;
    f32x4 acc = gemm_tile<8>(a8, Wqk_b + (size_t)(t * 16 + m16) * 256 + quad * 8,
                             bqk[t * 16 + m16]);
#pragma unroll
    for (int r = 0; r < 4; ++r)
      qk[(size_t)(bb * 16 + quad * 4 + r) * 256 + t * 16 + m16] = acc[r] * 0.0625f;
  }
}

template <bool FIRST>
__global__ __launch_bounds__(256) void k_attn(const float* __restrict__ xin,
                                              unsigned* __restrict__ xbf,
                                              const float* __restrict__ qk,
                                              float* __restrict__ pl,
                                              float* __restrict__ pu) {
  __shared__ __align__(16) unsigned xt[128 * 65];
  __shared__ __align__(16) unsigned pp[32 * 17];
  __shared__ __align__(16) float lred[4][16];
  const int u = (int)blockIdx.y * CH + (int)blockIdx.x;
  attn_unit(xin, xbf, qk, pl, pu, xt, pp, lred, u, FIRST, threadIdx.x);
}

__global__ __launch_bounds__(512) void k_upd(
    const float* __restrict__ pl, const float* __restrict__ pu,
    const unsigned short* __restrict__ Wv_b, const float* __restrict__ bv,
    const unsigned short* __restrict__ Wzr_b, const float* __restrict__ bzr,
    const unsigned short* __restrict__ Win_b, const float* __restrict__ bin,
    const unsigned short* __restrict__ Whn_b, const float* __restrict__ bhn,
    const unsigned short* __restrict__ W1_b, const float* __restrict__ b1,
    const unsigned short* __restrict__ W2_b, const float* __restrict__ b2,
    const float* __restrict__ gml, const float* __restrict__ bml,
    const float* __restrict__ gsl, const float* __restrict__ bsl,
    const unsigned short* __restrict__ Wqk_b, const float* __restrict__ bqk,
    float* __restrict__ slots, float* __restrict__ qk, float* __restrict__ dout) {
  __shared__ __align__(16) unsigned short cat[16 * 520];
  __shared__ __align__(16) float sp[16 * 260];
  __shared__ __align__(16) float s1[16 * 260];
  __shared__ __align__(16) unsigned short lnb[16 * 264];
  const int tid = threadIdx.x, bb = blockIdx.x;
  const int lane = tid & 63, wave = tid >> 6;
  const int m16 = lane & 15, quad = lane >> 4;
  const int row = tid >> 5, l32 = tid & 31, d0 = l32 * 8;
  const int bat = 2 * bb + (row >> 3), sl = row & 7;
  {
    float L = 0.f;
#pragma unroll
    for (int cc = 0; cc < 16; ++cc) L += pl[(bat * 16 + cc) * 8 + sl];
    float li = 1.f / L;
    float a[8] = {0.f, 0.f, 0.f, 0.f, 0.f, 0.f, 0.f, 0.f};
    for (int cc = 0; cc < 16; ++cc) {
      const float* pp_ = pu + ((size_t)(bat * 16 + cc) * 8 + sl) * 256 + d0;
      float4 v0 = *(const float4*)pp_, v1 = *(const float4*)(pp_ + 4);
      a[0] += v0.x; a[1] += v0.y; a[2] += v0.z; a[3] += v0.w;
      a[4] += v1.x; a[5] += v1.y; a[6] += v1.z; a[7] += v1.w;
    }
    uint4 o;
    o.x = bfpack2(a[0] * li, a[1] * li); o.y = bfpack2(a[2] * li, a[3] * li);
    o.z = bfpack2(a[4] * li, a[5] * li); o.w = bfpack2(a[6] * li, a[7] * li);
    *(uint4*)(cat + row * 520 + d0) = o;
    const float* sp_ = slots + (size_t)(bb * 16 + row) * 256 + d0;
    float4 h0 = *(const float4*)sp_, h1 = *(const float4*)(sp_ + 4);
    *(float4*)(sp + row * 260 + d0) = h0;
    *(float4*)(sp + row * 260 + d0 + 4) = h1;
    uint4 hb;
    hb.x = bfpack2(h0.x, h0.y); hb.y = bfpack2(h0.z, h0.w);
    hb.z = bfpack2(h1.x, h1.y); hb.w = bfpack2(h1.z, h1.w);
    *(uint4*)(cat + row * 520 + 256 + d0) = hb;
  }
  __syncthreads();
  short8 afr[16];
  load_af<8>(afr, cat, 520, m16, quad);
  f32x4 accv[2];
#pragma unroll
  for (int i = 0; i < 2; ++i) {
    int t = wave + 8 * i;
    accv[i] = gemm_tile<8>(afr, Wv_b + (size_t)(t * 16 + m16) * 256 + quad * 8,
                           bv[t * 16 + m16]);
  }
  __syncthreads();
#pragma unroll
  for (int i = 0; i < 2; ++i) {
    int t = wave + 8 * i;
#pragma unroll
    for (int r = 0; r < 4; ++r)
      cat[(quad * 4 + r) * 520 + t * 16 + m16] = bf16r(accv[i][r]);
  }
  __syncthreads();
  load_af<16>(afr, cat, 520, m16, quad);
  f32x4 rr[2], zz[2];
#pragma unroll
  for (int i = 0; i < 2; ++i) {
    int t = wave + 8 * i;
    f32x4 ar = gemm_tile<16>(afr, Wzr_b + (size_t)(t * 16 + m16) * 512 + quad * 8,
                             bzr[t * 16 + m16]);
    f32x4 az = gemm_tile<16>(afr, Wzr_b + (size_t)((t + 16) * 16 + m16) * 512 + quad * 8,
                             bzr[(t + 16) * 16 + m16]);
#pragma unroll
    for (int r = 0; r < 4; ++r) { rr[i][r] = sigm(ar[r]); zz[i][r] = sigm(az[r]); }
  }
#pragma unroll
  for (int i = 0; i < 2; ++i) {
    int t = wave + 8 * i, col = t * 16 + m16;
    f32x4 ain = gemm_tile<8>(afr, Win_b + (size_t)(t * 16 + m16) * 256 + quad * 8,
                             bin[col]);
    f32x4 ahn = gemm_tile<8>(afr + 8, Whn_b + (size_t)(t * 16 + m16) * 256 + quad * 8,
                             bhn[col]);
#pragma unroll
    for (int r = 0; r < 4; ++r) {
      int rw = quad * 4 + r;
      float nin = ain[r] + rr[i][r] * ahn[r];
      float nn = 1.f - 2.f / (__expf(2.f * nin) + 1.f);
      float hpc = sp[rw * 260 + col];
      s1[rw * 260 + col] = hpc + (1.f - zz[i][r]) * nn + zz[i][r] * hpc;
    }
  }
  __syncthreads();
  {
    const float* s1r = s1 + row * 260 + d0;
    float4 v0 = *(const float4*)s1r, v1 = *(const float4*)(s1r + 4);
    float x[8] = {v0.x, v0.y, v0.z, v0.w, v1.x, v1.y, v1.z, v1.w};
    ln_row8(x, gml, bml, d0, lnb + row * 264 + d0);
  }
  __syncthreads();
  load_af<8>(afr, lnb, 264, m16, quad);
#pragma unroll
  for (int i = 0; i < 2; ++i) {
    int t = wave + 8 * i;
    f32x4 acc = gemm_tile<8>(afr, W1_b + (size_t)(t * 16 + m16) * 256 + quad * 8,
                             b1[t * 16 + m16]);
#pragma unroll
    for (int r = 0; r < 4; ++r)
      cat[(quad * 4 + r) * 520 + t * 16 + m16] = bf16r(fmaxf(acc[r], 0.f));
  }
  __syncthreads();
  load_af<8>(afr, cat, 520, m16, quad);
#pragma unroll
  for (int i = 0; i < 2; ++i) {
    int t = wave + 8 * i;
    f32x4 acc = gemm_tile<8>(afr, W2_b + (size_t)(t * 16 + m16) * 256 + quad * 8,
                             b2[t * 16 + m16]);
#pragma unroll
    for (int r = 0; r < 4; ++r) {
      int rw = quad * 4 + r, col = t * 16 + m16;
      float v = acc[r] + s1[rw * 260 + col];
      size_t gi = (size_t)(bb * 16 + rw) * 256 + col;
      slots[gi] = v;
      if (dout) dout[gi] = v;
      sp[rw * 260 + col] = v;
    }
  }
  __syncthreads();
  {
    const float* spr = sp + row * 260 + d0;
    float4 v0 = *(const float4*)spr, v1 = *(const float4*)(spr + 4);
    float x[8] = {v0.x, v0.y, v0.z, v0.w, v1.x, v1.y, v1.z, v1.w};
    ln_row8(x, gsl, bsl, d0, lnb + row * 264 + d0);
  }
  __syncthreads();
  load_af<8>(afr, lnb, 264, m16, quad);
#pragma unroll
  for (int i = 0; i < 2; ++i) {
    int t = wave + 8 * i;
    f32x4 acc = gemm_tile<8>(afr, Wqk_b + (size_t)(t * 16 + m16) * 256 + quad * 8,
                             bqk[t * 16 + m16]);
#pragma unroll
    for (int r = 0; r < 4; ++r)
      qk[(size_t)(bb * 16 + quad * 4 + r) * 256 + t * 16 + m16] = acc[r] * 0.0625f;
  }
}

// ---------------- launch ----------------
extern "C" void kernel_launch(void* const* d_in, const int* in_sizes, int n_in,
                              void* d_out, int out_size, void* d_ws, size_t ws_size,
                              hipStream_t stream) {
  const float* inputs = (const float*)d_in[0];
  const float* noise = (const float*)d_in[1];
  const float* s_mu = (const float*)d_in[2];
  const float* s_sg = (const float*)d_in[3];
  const float* Wq = (const float*)d_in[4];
  const float* bq = (const float*)d_in[5];
  const float* Wk = (const float*)d_in[6];
  // d_in[7] = bk: unused (softmax-invariant)
  const float* Wv = (const float*)d_in[8];
  const float* bv = (const float*)d_in[9];
  const float* Wih = (const float*)d_in[10];
  const float* bih = (const float*)d_in[11];
  const float* Whh = (const float*)d_in[12];
  const float* bhh = (const float*)d_in[13];
  const float* W1 = (const float*)d_in[14];
  const float* b1 = (const float*)d_in[15];
  const float* W2 = (const float*)d_in[16];
  const float* b2 = (const float*)d_in[17];
  const float* gsl = (const float*)d_in[18];
  const float* bsl = (const float*)d_in[19];
  const float* gml = (const float*)d_in[20];
  const float* bml = (const float*)d_in[21];
  float* out = (float*)d_out;

  char* wsb = (char*)d_ws;
  unsigned* xbf = (unsigned*)wsb;  // bf16 copy of inputs: 128 MiB
  float* fp = (float*)(wsb + (size_t)Bn * Nn * Dd * 2);
  float* slots = fp; fp += Bn * Ss * Dd;
  float* qk = fp;    fp += Bn * Ss * Dd;
  float* bqk = fp;   fp += Dd;
  float* pl = fp;    fp += Bn * CH * Ss;
  float* pu = fp;    fp += Bn * CH * Ss * Dd;
  float* bzr = fp;   fp += 512;
  unsigned short* wb = (unsigned short*)fp;
  unsigned short* Wv_b = wb;  wb += 65536;
  unsigned short* Wzr_b = wb; wb += 262144;
  unsigned short* Win_b = wb; wb += 65536;
  unsigned short* Whn_b = wb; wb += 65536;
  unsigned short* W1_b = wb;  wb += 65536;
  unsigned short* W2_b = wb;  wb += 65536;
  unsigned short* Wqk_b = wb; wb += 65536;
  (void)in_sizes; (void)n_in; (void)out_size; (void)ws_size;

  MegaArgs ma;
  ma.inputs = inputs; ma.noise = noise; ma.s_mu = s_mu; ma.s_sg = s_sg;
  ma.Wq = Wq; ma.bq = bq; ma.Wk = Wk; ma.Wv = Wv; ma.bv = bv;
  ma.Wih = Wih; ma.bih = bih; ma.Whh = Whh; ma.bhh = bhh;
  ma.W1 = W1; ma.b1 = b1; ma.W2 = W2; ma.b2 = b2;
  ma.gsl = gsl; ma.bsl = bsl; ma.gml = gml; ma.bml = bml;
  ma.xbf = xbf; ma.slots = slots; ma.qk = qk; ma.bqk = bqk;
  ma.pl = pl; ma.pu = pu; ma.bzr = bzr;
  ma.Wv_b = Wv_b; ma.Wzr_b = Wzr_b; ma.Win_b = Win_b; ma.Whn_b = Whn_b;
  ma.W1_b = W1_b; ma.W2_b = W2_b; ma.Wqk_b = Wqk_b;
  ma.out = out;
  void* kargs[] = {(void*)&ma};
  hipError_t err = hipLaunchCooperativeKernel((const void*)k_mega, dim3(1024),
                                              dim3(256), kargs, 0, stream);
  if (err != hipSuccess) {
    (void)hipGetLastError();  // clear sticky error; fall back to benched R7 path
    k_wqk<<<dim3(257), dim3(256), 0, stream>>>(Wq, Wk, bq, Wqk_b, bqk);
    k_conv<<<dim3(1154), dim3(256), 0, stream>>>(
        Wv, Wih, Whh, W1, W2, bih, bhh, (unsigned*)Wv_b, (unsigned*)Wzr_b,
        (unsigned*)Win_b, (unsigned*)Whn_b, (unsigned*)W1_b, (unsigned*)W2_b, bzr);
    k_qk0<<<dim3(32), dim3(512), 0, stream>>>(noise, s_mu, s_sg, gsl, bsl, Wqk_b, bqk,
                                              slots, qk);
    for (int it = 0; it < 3; ++it) {
      if (it == 0)
        k_attn<true><<<dim3(CH, Bn), dim3(256), 0, stream>>>(inputs, xbf, qk, pl, pu);
      else
        k_attn<false><<<dim3(CH, Bn), dim3(256), 0, stream>>>(nullptr, xbf, qk, pl, pu);
      k_upd<<<dim3(32), dim3(512), 0, stream>>>(
          pl, pu, Wv_b, bv, Wzr_b, bzr, Win_b, bih + 512, Whn_b, bhh + 512, W1_b, b1,
          W2_b, b2, gml, bml, gsl, bsl, Wqk_b, bqk, slots, qk, (it == 2) ? out : nullptr);
    }
  }
}

// Round 5
// 685.076 us; speedup vs baseline: 3.7837x; 3.7837x over previous
//
#include <hip/hip_runtime.h>
#include <hip/hip_cooperative_groups.h>

namespace cg = cooperative_groups;

// SlotAttention, algebraically restructured:
//   logits = (LN(slots) @ (Wq^T @ Wk)) . x / 16   (q.bk term dropped: softmax-invariant)
//   updates = softmax-weighted-avg(x) @ Wv^T + bv  (attn rows sum to 1)
// R5-R7: attn pipeline variants all FLAT at ~683us (9-dispatch path).
// R8: cooperative mega-kernel probe. Result: __launch_bounds__(256,4) capped regs
//     at 64 VGPR -> massive scratch spill (WRITE 501MB vs ~160 ideal, VALUBusy 1.5%,
//     dur 2320us). The probe DID prove mega runs correctly (passed, absmax 0.125).
// R9: same mega, spill removed: __launch_bounds__(256) (no wave clamp), all phases
//     grid-stride, host picks grid = min(1024, occupancy*256) so cooperative launch
//     is always legal regardless of compiler's VGPR choice. Fallback = R7 path.

constexpr int Bn = 64;    // batch
constexpr int Nn = 4096;  // inputs per batch
constexpr int Dd = 256;   // feature dim (== IN_D)
constexpr int Ss = 8;     // slots
constexpr int CH = 16;    // N-chunks per batch for attention
constexpr float EPSF = 1e-5f;

#define DEV __device__ __forceinline__

using short8 = __attribute__((ext_vector_type(8))) short;
using f32x4 = __attribute__((ext_vector_type(4))) float;
union U8 { short8 s; uint4 u; };

DEV unsigned bfpack2(float lo, float hi) {
  unsigned ul = __float_as_uint(lo), uh = __float_as_uint(hi);
  ul = (ul + 0x7FFFu + ((ul >> 16) & 1u)) >> 16;         // RNE to bf16
  uh = (uh + 0x7FFFu + ((uh >> 16) & 1u)) & 0xFFFF0000u;
  return ul | uh;
}
DEV unsigned short bf16r(float x) {
  unsigned u = __float_as_uint(x);
  u = (u + 0x7FFFu + ((u >> 16) & 1u)) >> 16;
  return (unsigned short)u;
}
DEV float rsum32(float v) {  // sum within each 32-lane half of a wave
  v += __shfl_xor(v, 1); v += __shfl_xor(v, 2); v += __shfl_xor(v, 4);
  v += __shfl_xor(v, 8); v += __shfl_xor(v, 16);
  return v;
}
DEV float sigm(float x) { return 1.f / (1.f + __expf(-x)); }

// ---- MFMA tile helpers: C[row=quad*4+r][col=t*16+m16] = sum_k A[row][k] W[col][k] + b
template <int NK>
DEV void load_af(short8* a, const unsigned short* base, int lda, int m16, int quad) {
  const unsigned short* p = base + m16 * lda + quad * 8;
#pragma unroll
  for (int kk = 0; kk < NK; ++kk) a[kk] = *(const short8*)(p + kk * 32);
}
template <int NK>
DEV f32x4 gemm_tile(const short8* a, const unsigned short* wr, float binit) {
  f32x4 acc = {binit, binit, binit, binit};
#pragma unroll
  for (int kk = 0; kk < NK; ++kk) {
    short8 b = *(const short8*)(wr + kk * 32);
    acc = __builtin_amdgcn_mfma_f32_16x16x32_bf16(a[kk], b, acc, 0, 0, 0);
  }
  return acc;
}

// LayerNorm over one 256-row held 8-per-thread by 32 lanes; writes bf16 packed out.
DEV void ln_row8(const float* x, const float* g, const float* b, int d0,
                 unsigned short* dst) {
  float s = x[0] + x[1] + x[2] + x[3] + x[4] + x[5] + x[6] + x[7];
  float mu = rsum32(s) * (1.f / 256.f);
  float q = 0.f;
#pragma unroll
  for (int j = 0; j < 8; ++j) { float d = x[j] - mu; q += d * d; }
  float rs = rsqrtf(rsum32(q) * (1.f / 256.f) + EPSF);
  float o[8];
#pragma unroll
  for (int j = 0; j < 8; ++j) o[j] = (x[j] - mu) * rs * g[d0 + j] + b[d0 + j];
  uint4 w;
  w.x = bfpack2(o[0], o[1]); w.y = bfpack2(o[2], o[3]);
  w.z = bfpack2(o[4], o[5]); w.w = bfpack2(o[6], o[7]);
  *(uint4*)dst = w;
}

// ================= shared device bodies =================

template <bool FIRST>
DEV void ld_chunk_t(const float* __restrict__ xin, unsigned* __restrict__ xbf,
                    size_t nbase, int tid, uint4* pr) {
#pragma unroll
  for (int i = 0; i < 8; ++i) {
    int flat = i * 256 + tid, n = flat >> 5, od = flat & 31;
    if (FIRST) {
      const float4* src = (const float4*)(xin + (nbase + n) * 256 + od * 8);
      float4 v0 = src[0], v1 = src[1];
      uint4 o;
      o.x = bfpack2(v0.x, v0.y); o.y = bfpack2(v0.z, v0.w);
      o.z = bfpack2(v1.x, v1.y); o.w = bfpack2(v1.z, v1.w);
      ((uint4*)xbf)[(nbase + n) * 32 + od] = o;
      pr[i] = o;
    } else {
      pr[i] = ((const uint4*)xbf)[(nbase + n) * 32 + od];
    }
  }
}
DEV void ld_chunk_rt(bool first, const float* __restrict__ xin,
                     unsigned* __restrict__ xbf, size_t nbase, int tid, uint4* pr) {
  if (first) ld_chunk_t<true>(xin, xbf, nbase, tid, pr);
  else ld_chunk_t<false>(xin, xbf, nbase, tid, pr);
}

DEV void attn_unit(const float* __restrict__ xin, unsigned* __restrict__ xbf,
                   const float* __restrict__ qk, float* __restrict__ pl,
                   float* __restrict__ pu, unsigned* xt, unsigned* pp,
                   float (*lred)[16], int u, bool first, int tid) {
  const int lane = tid & 63, wave = tid >> 6;
  const int m16 = lane & 15, quad = lane >> 4;
  const int b = u >> 4, c = u & 15;
  const int pb = u * 8;
  const unsigned psel = (m16 & 1) ? 0x07060302u : 0x05040100u;

  short8 aq[8];
  {
    const float* qrow = qk + (size_t)(b * 8 + (m16 & 7)) * 256 + quad * 8;
#pragma unroll
    for (int kk = 0; kk < 8; ++kk) {
      U8 f;
      float4 q0 = *(const float4*)(qrow + kk * 32);
      float4 q1 = *(const float4*)(qrow + kk * 32 + 4);
      f.u.x = bfpack2(q0.x, q0.y); f.u.y = bfpack2(q0.z, q0.w);
      f.u.z = bfpack2(q1.x, q1.y); f.u.w = bfpack2(q1.z, q1.w);
      if (m16 >= 8) { f.u.x = 0u; f.u.y = 0u; f.u.z = 0u; f.u.w = 0u; }
      aq[kk] = f.s;
    }
  }
  float lacc[4] = {0.f, 0.f, 0.f, 0.f};
  f32x4 acc[4];
#pragma unroll
  for (int t = 0; t < 4; ++t) acc[t] = (f32x4){0.f, 0.f, 0.f, 0.f};
  const int d0w = wave * 64;

  uint4 pr[8];
  const size_t nb0 = (size_t)b * Nn + (size_t)c * 256;
  ld_chunk_rt(first, xin, xbf, nb0, tid, pr);

  for (int ch = 0; ch < 4; ++ch) {
#pragma unroll
    for (int i = 0; i < 8; ++i) {
      int flat = i * 256 + tid, n = flat >> 5, od = flat & 31, rb = od * 4;
      xt[(rb + 0) * 65 + n] = pr[i].x;
      xt[(rb + 1) * 65 + n] = pr[i].y;
      xt[(rb + 2) * 65 + n] = pr[i].z;
      xt[(rb + 3) * 65 + n] = pr[i].w;
    }
    __syncthreads();
    if (ch + 1 < 4)
      ld_chunk_rt(first, xin, xbf, nb0 + (size_t)(ch + 1) * 64, tid, pr);
    // phase A: wave w computes n-tile nt=w
    {
      const int nt = wave;
      f32x4 pacc = (f32x4){0.f, 0.f, 0.f, 0.f};
#pragma unroll
      for (int kk = 0; kk < 8; ++kk) {
        int base = (kk * 16 + quad * 4) * 65 + nt * 16 + m16;
        U8 bf;
        bf.u.x = xt[base]; bf.u.y = xt[base + 65];
        bf.u.z = xt[base + 130]; bf.u.w = xt[base + 195];
        pacc = __builtin_amdgcn_mfma_f32_16x16x32_bf16(aq[kk], bf.s, pacc, 0, 0, 0);
      }
      const int xrow = nt * 16 + m16;
      unsigned short* pps = (unsigned short*)pp;
#pragma unroll
      for (int r = 0; r < 4; ++r) {
        float p = __expf(pacc[r]);  // |logit| small: no max-shift needed
        lacc[r] += p;
        pps[((xrow >> 1) * 17 + quad * 4 + r) * 2 + (xrow & 1)] = bf16r(p);
      }
    }
    __syncthreads();
    // phase B: wave owns 64 d-cols
#pragma unroll
    for (int nh = 0; nh < 2; ++nh) {
      U8 bp;
      bp.u.x = pp[(nh * 16 + quad * 4 + 0) * 17 + m16];
      bp.u.y = pp[(nh * 16 + quad * 4 + 1) * 17 + m16];
      bp.u.z = pp[(nh * 16 + quad * 4 + 2) * 17 + m16];
      bp.u.w = pp[(nh * 16 + quad * 4 + 3) * 17 + m16];
#pragma unroll
      for (int t = 0; t < 4; ++t) {
        int d = d0w + t * 16 + m16;
        const unsigned* xr = xt + (d >> 1) * 65 + nh * 32 + quad * 8;
        unsigned u0 = xr[0], u1 = xr[1], u2 = xr[2], u3 = xr[3];
        unsigned u4 = xr[4], u5 = xr[5], u6 = xr[6], u7 = xr[7];
        U8 af;
        af.u.x = __builtin_amdgcn_perm(u1, u0, psel);
        af.u.y = __builtin_amdgcn_perm(u3, u2, psel);
        af.u.z = __builtin_amdgcn_perm(u5, u4, psel);
        af.u.w = __builtin_amdgcn_perm(u7, u6, psel);
        acc[t] = __builtin_amdgcn_mfma_f32_16x16x32_bf16(af.s, bp.s, acc[t], 0, 0, 0);
      }
    }
    __syncthreads();
  }
  if (m16 < 8) {
#pragma unroll
    for (int t = 0; t < 4; ++t)
#pragma unroll
      for (int r = 0; r < 4; ++r)
        pu[(size_t)(pb + m16) * 256 + d0w + t * 16 + quad * 4 + r] = acc[t][r];
  }
#pragma unroll
  for (int r = 0; r < 4; ++r) {
    float v = lacc[r];
    v += __shfl_xor(v, 1); v += __shfl_xor(v, 2);
    v += __shfl_xor(v, 4); v += __shfl_xor(v, 8);
    if (m16 == 0) lred[wave][quad * 4 + r] = v;
  }
  __syncthreads();
  if (tid < 8)
    pl[pb + tid] = lred[0][tid] + lred[1][tid] + lred[2][tid] + lred[3][tid];
}

// ---- 256-thread slot-update body (mega): 16 rows, 4 tiles/wave, s1 in-place in sp,
//      LN buffer aliased onto cat cols [256,520) ----
DEV void upd_body256(
    const float* __restrict__ pl, const float* __restrict__ pu,
    const unsigned short* __restrict__ Wv_b, const float* __restrict__ bv,
    const unsigned short* __restrict__ Wzr_b, const float* __restrict__ bzr,
    const unsigned short* __restrict__ Win_b, const float* __restrict__ bin,
    const unsigned short* __restrict__ Whn_b, const float* __restrict__ bhn,
    const unsigned short* __restrict__ W1_b, const float* __restrict__ b1,
    const unsigned short* __restrict__ W2_b, const float* __restrict__ b2,
    const float* __restrict__ gml, const float* __restrict__ bml,
    const float* __restrict__ gsl, const float* __restrict__ bsl,
    const unsigned short* __restrict__ Wqk_b, const float* __restrict__ bqk,
    float* __restrict__ slots, float* __restrict__ qk, float* __restrict__ dout,
    unsigned short* cat, float* sp, int bb, int tid) {
  unsigned short* lnbp = cat + 256;  // per-row cols [256,520), stride 520
  const int lane = tid & 63, wave4 = tid >> 6;
  const int m16 = lane & 15, quad = lane >> 4;
  const int row8 = tid >> 5, l32 = tid & 31, d0 = l32 * 8;
  // step 1: combine
#pragma unroll
  for (int r2 = 0; r2 < 2; ++r2) {
    const int row = row8 + 8 * r2;
    const int bat = 2 * bb + (row >> 3), sl = row & 7;
    float L = 0.f;
#pragma unroll
    for (int cc = 0; cc < 16; ++cc) L += pl[(bat * 16 + cc) * 8 + sl];
    float li = 1.f / L;
    float a[8] = {0.f, 0.f, 0.f, 0.f, 0.f, 0.f, 0.f, 0.f};
    for (int cc = 0; cc < 16; ++cc) {
      const float* pp_ = pu + ((size_t)(bat * 16 + cc) * 8 + sl) * 256 + d0;
      float4 v0 = *(const float4*)pp_, v1 = *(const float4*)(pp_ + 4);
      a[0] += v0.x; a[1] += v0.y; a[2] += v0.z; a[3] += v0.w;
      a[4] += v1.x; a[5] += v1.y; a[6] += v1.z; a[7] += v1.w;
    }
    uint4 o;
    o.x = bfpack2(a[0] * li, a[1] * li); o.y = bfpack2(a[2] * li, a[3] * li);
    o.z = bfpack2(a[4] * li, a[5] * li); o.w = bfpack2(a[6] * li, a[7] * li);
    *(uint4*)(cat + row * 520 + d0) = o;
    const float* sp_ = slots + (size_t)(bb * 16 + row) * 256 + d0;
    float4 h0 = *(const float4*)sp_, h1 = *(const float4*)(sp_ + 4);
    *(float4*)(sp + row * 260 + d0) = h0;
    *(float4*)(sp + row * 260 + d0 + 4) = h1;
    uint4 hb;
    hb.x = bfpack2(h0.x, h0.y); hb.y = bfpack2(h0.z, h0.w);
    hb.z = bfpack2(h1.x, h1.y); hb.w = bfpack2(h1.z, h1.w);
    *(uint4*)(cat + row * 520 + 256 + d0) = hb;
  }
  __syncthreads();
  // step 2: updates = u' @ Wv^T + bv
  short8 afr[16];
  load_af<8>(afr, cat, 520, m16, quad);
  f32x4 accv[4];
#pragma unroll
  for (int i = 0; i < 4; ++i) {
    int t = wave4 + 4 * i;
    accv[i] = gemm_tile<8>(afr, Wv_b + (size_t)(t * 16 + m16) * 256 + quad * 8,
                           bv[t * 16 + m16]);
  }
  __syncthreads();
#pragma unroll
  for (int i = 0; i < 4; ++i) {
    int t = wave4 + 4 * i;
#pragma unroll
    for (int r = 0; r < 4; ++r)
      cat[(quad * 4 + r) * 520 + t * 16 + m16] = bf16r(accv[i][r]);
  }
  __syncthreads();
  // steps 3+4 merged per-tile: gates transient, slots1 written in-place into sp
  load_af<16>(afr, cat, 520, m16, quad);
#pragma unroll
  for (int i = 0; i < 4; ++i) {
    int t = wave4 + 4 * i, col = t * 16 + m16;
    f32x4 ar = gemm_tile<16>(afr, Wzr_b + (size_t)(t * 16 + m16) * 512 + quad * 8,
                             bzr[t * 16 + m16]);
    f32x4 az = gemm_tile<16>(afr, Wzr_b + (size_t)((t + 16) * 16 + m16) * 512 + quad * 8,
                             bzr[(t + 16) * 16 + m16]);
    f32x4 ain = gemm_tile<8>(afr, Win_b + (size_t)(t * 16 + m16) * 256 + quad * 8,
                             bin[col]);
    f32x4 ahn = gemm_tile<8>(afr + 8, Whn_b + (size_t)(t * 16 + m16) * 256 + quad * 8,
                             bhn[col]);
#pragma unroll
    for (int r = 0; r < 4; ++r) {
      int rw = quad * 4 + r;
      float rrv = sigm(ar[r]), zzv = sigm(az[r]);
      float nin = ain[r] + rrv * ahn[r];
      float nn = 1.f - 2.f / (__expf(2.f * nin) + 1.f);  // tanh
      float hpc = sp[rw * 260 + col];
      sp[rw * 260 + col] = hpc + (1.f - zzv) * nn + zzv * hpc;  // prev + h_new
    }
  }
  __syncthreads();
  // step 5: LN_mlp(slots1) -> lnbp
#pragma unroll
  for (int r2 = 0; r2 < 2; ++r2) {
    int row = row8 + 8 * r2;
    const float* s1r = sp + row * 260 + d0;
    float4 v0 = *(const float4*)s1r, v1 = *(const float4*)(s1r + 4);
    float x[8] = {v0.x, v0.y, v0.z, v0.w, v1.x, v1.y, v1.z, v1.w};
    ln_row8(x, gml, bml, d0, lnbp + row * 520 + d0);
  }
  __syncthreads();
  // step 6: hid = relu(LN_mlp @ W1^T + b1) -> cat[:,0:256)
  load_af<8>(afr, lnbp, 520, m16, quad);
#pragma unroll
  for (int i = 0; i < 4; ++i) {
    int t = wave4 + 4 * i;
    f32x4 acc = gemm_tile<8>(afr, W1_b + (size_t)(t * 16 + m16) * 256 + quad * 8,
                             b1[t * 16 + m16]);
#pragma unroll
    for (int r = 0; r < 4; ++r)
      cat[(quad * 4 + r) * 520 + t * 16 + m16] = bf16r(fmaxf(acc[r], 0.f));
  }
  __syncthreads();
  // step 7: slots2 = slots1 + hid @ W2^T + b2 (in-place into sp) + global
  load_af<8>(afr, cat, 520, m16, quad);
#pragma unroll
  for (int i = 0; i < 4; ++i) {
    int t = wave4 + 4 * i;
    f32x4 acc = gemm_tile<8>(afr, W2_b + (size_t)(t * 16 + m16) * 256 + quad * 8,
                             b2[t * 16 + m16]);
#pragma unroll
    for (int r = 0; r < 4; ++r) {
      int rw = quad * 4 + r, col = t * 16 + m16;
      float v = acc[r] + sp[rw * 260 + col];
      size_t gi = (size_t)(bb * 16 + rw) * 256 + col;
      slots[gi] = v;
      if (dout) dout[gi] = v;
      sp[rw * 260 + col] = v;
    }
  }
  __syncthreads();
  // step 8: LN_slots(slots2) -> lnbp
#pragma unroll
  for (int r2 = 0; r2 < 2; ++r2) {
    int row = row8 + 8 * r2;
    const float* spr = sp + row * 260 + d0;
    float4 v0 = *(const float4*)spr, v1 = *(const float4*)(spr + 4);
    float x[8] = {v0.x, v0.y, v0.z, v0.w, v1.x, v1.y, v1.z, v1.w};
    ln_row8(x, gsl, bsl, d0, lnbp + row * 520 + d0);
  }
  __syncthreads();
  // step 9: q' = (LN_slots @ WqkT + bqk)/16
  load_af<8>(afr, lnbp, 520, m16, quad);
#pragma unroll
  for (int i = 0; i < 4; ++i) {
    int t = wave4 + 4 * i;
    f32x4 acc = gemm_tile<8>(afr, Wqk_b + (size_t)(t * 16 + m16) * 256 + quad * 8,
                             bqk[t * 16 + m16]);
#pragma unroll
    for (int r = 0; r < 4; ++r)
      qk[(size_t)(bb * 16 + quad * 4 + r) * 256 + t * 16 + m16] = acc[r] * 0.0625f;
  }
}

// ---- 256-thread init+qk0 body (mega): 16 rows/block, LN into cat-aliased lnbp ----
DEV void qk0_body256(const float* __restrict__ noise, const float* __restrict__ s_mu,
                     const float* __restrict__ s_sg, const float* __restrict__ gsl,
                     const float* __restrict__ bsl,
                     const unsigned short* __restrict__ Wqk_b,
                     const float* __restrict__ bqk, float* __restrict__ slots,
                     float* __restrict__ qk, unsigned short* cat, int bb, int tid) {
  unsigned short* lnbp = cat + 256;
  const int lane = tid & 63, wave4 = tid >> 6;
  const int m16 = lane & 15, quad = lane >> 4;
  const int row8 = tid >> 5, l32 = tid & 31, d0 = l32 * 8;
#pragma unroll
  for (int r2 = 0; r2 < 2; ++r2) {
    const int row = row8 + 8 * r2;
    const int grow = bb * 16 + row;
    const int sidx = (grow & 7) * 256 + d0;
    const float* np = noise + (size_t)grow * 256 + d0;
    float4 n0 = *(const float4*)np, n1 = *(const float4*)(np + 4);
    float4 m0 = *(const float4*)(s_mu + sidx), m1 = *(const float4*)(s_mu + sidx + 4);
    float4 g0 = *(const float4*)(s_sg + sidx), g1 = *(const float4*)(s_sg + sidx + 4);
    float x[8] = {m0.x + g0.x * n0.x, m0.y + g0.y * n0.y,
                  m0.z + g0.z * n0.z, m0.w + g0.w * n0.w,
                  m1.x + g1.x * n1.x, m1.y + g1.y * n1.y,
                  m1.z + g1.z * n1.z, m1.w + g1.w * n1.w};
    float* sp_ = slots + (size_t)grow * 256 + d0;
    float4 o0, o1;
    o0.x = x[0]; o0.y = x[1]; o0.z = x[2]; o0.w = x[3];
    o1.x = x[4]; o1.y = x[5]; o1.z = x[6]; o1.w = x[7];
    *(float4*)sp_ = o0; *(float4*)(sp_ + 4) = o1;
    ln_row8(x, gsl, bsl, d0, lnbp + row * 520 + d0);
  }
  __syncthreads();
  short8 a8[8];
  load_af<8>(a8, lnbp, 520, m16, quad);
#pragma unroll
  for (int i = 0; i < 4; ++i) {
    int t = wave4 + 4 * i;
    f32x4 acc = gemm_tile<8>(a8, Wqk_b + (size_t)(t * 16 + m16) * 256 + quad * 8,
                             bqk[t * 16 + m16]);
#pragma unroll
    for (int r = 0; r < 4; ++r)
      qk[(size_t)(bb * 16 + quad * 4 + r) * 256 + t * 16 + m16] = acc[r] * 0.0625f;
  }
}

// ---- prep unit: u<256 wqk col; u==256 bqk; u>=257 conv chunks ----
DEV void prep_unit(int u, int tid,
                   const float* Wq, const float* Wk, const float* bq,
                   unsigned short* Wqk_b, float* bqk,
                   const float* Wv, const float* Wih, const float* Whh,
                   const float* W1, const float* W2,
                   const float* bih, const float* bhh,
                   unsigned* Wv_b, unsigned* Wzr_b, unsigned* Win_b, unsigned* Whn_b,
                   unsigned* W1_b, unsigned* W2_b, float* bzr) {
  if (u < 256) {
    float acc = 0.f;
    for (int e = 0; e < 256; ++e) acc += Wq[e * 256 + tid] * Wk[e * 256 + u];
    Wqk_b[u * 256 + tid] = bf16r(acc);
  } else if (u == 256) {
    float acc = 0.f;
    for (int e = 0; e < 256; ++e) acc += bq[e] * Wk[e * 256 + tid];
    bqk[tid] = acc;
  } else {
    int cu = u - 257;
    if (cu >= 1152) {
      int i = (cu - 1152) * 256 + tid;
      if (i < 512) bzr[i] = bih[i] + bhh[i];
      return;
    }
    int p = cu * 256 + tid;
    const float* src; unsigned* dst;
    if (p < 32768) { src = Wv + 2 * p; dst = Wv_b + p; }
    else if (p < 163840) {
      int q = p - 32768, row = q >> 8, col = (q & 255) * 2;
      src = (col < 256) ? (Wih + row * 256 + col) : (Whh + row * 256 + col - 256);
      dst = Wzr_b + q;
    }
    else if (p < 196608) { int q = p - 163840; src = Wih + 512 * 256 + 2 * q; dst = Win_b + q; }
    else if (p < 229376) { int q = p - 196608; src = Whh + 512 * 256 + 2 * q; dst = Whn_b + q; }
    else if (p < 262144) { int q = p - 229376; src = W1 + 2 * q; dst = W1_b + q; }
    else { int q = p - 262144; src = W2 + 2 * q; dst = W2_b + q; }
    dst[0] = bfpack2(src[0], src[1]);
  }
}

// ================= mega cooperative kernel =================
struct MegaArgs {
  const float *inputs, *noise, *s_mu, *s_sg;
  const float *Wq, *bq, *Wk, *Wv, *bv, *Wih, *bih, *Whh, *bhh;
  const float *W1, *b1, *W2, *b2, *gsl, *bsl, *gml, *bml;
  unsigned* xbf;
  float *slots, *qk, *bqk, *pl, *pu, *bzr;
  unsigned short *Wv_b, *Wzr_b, *Win_b, *Whn_b, *W1_b, *W2_b, *Wqk_b;
  float* out;
};

__global__ __launch_bounds__(256) void k_mega(MegaArgs a) {
  __shared__ __align__(16) union SMU {
    struct { unsigned xt[128 * 65]; unsigned pp[32 * 17]; float lred[4][16]; } at;
    struct { unsigned short cat[16 * 520]; float sp[16 * 260]; } up;
  } sm;
  const int tid = threadIdx.x, bid = blockIdx.x;
  const int nb = (int)gridDim.x;
  cg::grid_group grid = cg::this_grid();
  // P0: wqk + conv
  for (int u = bid; u < 1411; u += nb)
    prep_unit(u, tid, a.Wq, a.Wk, a.bq, a.Wqk_b, a.bqk, a.Wv, a.Wih, a.Whh, a.W1,
              a.W2, a.bih, a.bhh, (unsigned*)a.Wv_b, (unsigned*)a.Wzr_b,
              (unsigned*)a.Win_b, (unsigned*)a.Whn_b, (unsigned*)a.W1_b,
              (unsigned*)a.W2_b, a.bzr);
  __threadfence();
  grid.sync();
  // P1: init slots + q0
  for (int bb = bid; bb < 32; bb += nb)
    qk0_body256(a.noise, a.s_mu, a.s_sg, a.gsl, a.bsl, a.Wqk_b, a.bqk, a.slots, a.qk,
                sm.up.cat, bb, tid);
  __threadfence();
  grid.sync();
  for (int it = 0; it < 3; ++it) {
    for (int u = bid; u < Bn * CH; u += nb)
      attn_unit(a.inputs, a.xbf, a.qk, a.pl, a.pu, sm.at.xt, sm.at.pp, sm.at.lred,
                u, it == 0, tid);
    __threadfence();
    grid.sync();
    for (int bb = bid; bb < 32; bb += nb)
      upd_body256(a.pl, a.pu, a.Wv_b, a.bv, a.Wzr_b, a.bzr, a.Win_b, a.bih + 512,
                  a.Whn_b, a.bhh + 512, a.W1_b, a.b1, a.W2_b, a.b2, a.gml, a.bml,
                  a.gsl, a.bsl, a.Wqk_b, a.bqk, a.slots, a.qk,
                  (it == 2) ? a.out : nullptr, sm.up.cat, sm.up.sp, bb, tid);
    __threadfence();
    grid.sync();
  }
}

// ================= legacy fallback kernels (benched R7 path) =================
__global__ __launch_bounds__(256) void k_wqk(const float* __restrict__ Wq,
                                             const float* __restrict__ Wk,
                                             const float* __restrict__ bq,
                                             unsigned short* __restrict__ Wqk_b,
                                             float* __restrict__ bqk) {
  int tid = threadIdx.x, c = blockIdx.x;
  if (c < 256) {
    float acc = 0.f;
    for (int e = 0; e < 256; ++e) acc += Wq[e * 256 + tid] * Wk[e * 256 + c];
    Wqk_b[c * 256 + tid] = bf16r(acc);
  } else {
    float acc = 0.f;
    for (int e = 0; e < 256; ++e) acc += bq[e] * Wk[e * 256 + tid];
    bqk[tid] = acc;
  }
}

__global__ __launch_bounds__(256) void k_conv(
    const float* __restrict__ Wv, const float* __restrict__ Wih,
    const float* __restrict__ Whh, const float* __restrict__ W1,
    const float* __restrict__ W2,
    const float* __restrict__ bih, const float* __restrict__ bhh,
    unsigned* Wv_b, unsigned* Wzr_b, unsigned* Win_b, unsigned* Whn_b,
    unsigned* W1_b, unsigned* W2_b, float* bzr) {
  if (blockIdx.x >= 1152) {
    int i = (blockIdx.x - 1152) * 256 + threadIdx.x;
    if (i < 512) bzr[i] = bih[i] + bhh[i];
    return;
  }
  int p = blockIdx.x * 256 + threadIdx.x;
  const float* src; unsigned* dst;
  if (p < 32768) { src = Wv + 2 * p; dst = Wv_b + p; }
  else if (p < 163840) {
    int q = p - 32768, row = q >> 8, col = (q & 255) * 2;
    src = (col < 256) ? (Wih + row * 256 + col) : (Whh + row * 256 + col - 256);
    dst = Wzr_b + q;
  }
  else if (p < 196608) { int q = p - 163840; src = Wih + 512 * 256 + 2 * q; dst = Win_b + q; }
  else if (p < 229376) { int q = p - 196608; src = Whh + 512 * 256 + 2 * q; dst = Whn_b + q; }
  else if (p < 262144) { int q = p - 229376; src = W1 + 2 * q; dst = W1_b + q; }
  else { int q = p - 262144; src = W2 + 2 * q; dst = W2_b + q; }
  dst[0] = bfpack2(src[0], src[1]);
}

__global__ __launch_bounds__(512) void k_qk0(const float* __restrict__ noise,
                                             const float* __restrict__ s_mu,
                                             const float* __restrict__ s_sg,
                                             const float* __restrict__ gsl,
                                             const float* __restrict__ bsl,
                                             const unsigned short* __restrict__ Wqk_b,
                                             const float* __restrict__ bqk,
                                             float* __restrict__ slots,
                                             float* __restrict__ qk) {
  __shared__ __align__(16) unsigned short lnb[16 * 264];
  const int tid = threadIdx.x, bb = blockIdx.x;
  const int lane = tid & 63, wave = tid >> 6;
  const int m16 = lane & 15, quad = lane >> 4;
  const int row = tid >> 5, l32 = tid & 31, d0 = l32 * 8;
  {
    const int grow = bb * 16 + row;
    const int sidx = (grow & 7) * 256 + d0;
    const float* np = noise + (size_t)grow * 256 + d0;
    float4 n0 = *(const float4*)np, n1 = *(const float4*)(np + 4);
    float4 m0 = *(const float4*)(s_mu + sidx), m1 = *(const float4*)(s_mu + sidx + 4);
    float4 g0 = *(const float4*)(s_sg + sidx), g1 = *(const float4*)(s_sg + sidx + 4);
    float x[8] = {m0.x + g0.x * n0.x, m0.y + g0.y * n0.y,
                  m0.z + g0.z * n0.z, m0.w + g0.w * n0.w,
                  m1.x + g1.x * n1.x, m1.y + g1.y * n1.y,
                  m1.z + g1.z * n1.z, m1.w + g1.w * n1.w};
    float* sp_ = slots + (size_t)grow * 256 + d0;
    float4 o0, o1;
    o0.x = x[0]; o0.y = x[1]; o0.z = x[2]; o0.w = x[3];
    o1.x = x[4]; o1.y = x[5]; o1.z = x[6]; o1.w = x[7];
    *(float4*)sp_ = o0; *(float4*)(sp_ + 4) = o1;
    ln_row8(x, gsl, bsl, d0, lnb + row * 264 + d0);
  }
  __syncthreads();
  short8 a8[8];
  load_af<8>(a8, lnb, 264, m16, quad);
#pragma unroll
  for (int i = 0; i < 2; ++i) {
    int t = wave + 8 * i;
    f32x4 acc = gemm_tile<8>(a8, Wqk_b + (size_t)(t * 16 + m16) * 256 + quad * 8,
                             bqk[t * 16 + m16]);
#pragma unroll
    for (int r = 0; r < 4; ++r)
      qk[(size_t)(bb * 16 + quad * 4 + r) * 256 + t * 16 + m16] = acc[r] * 0.0625f;
  }
}

template <bool FIRST>
__global__ __launch_bounds__(256) void k_attn(const float* __restrict__ xin,
                                              unsigned* __restrict__ xbf,
                                              const float* __restrict__ qk,
                                              float* __restrict__ pl,
                                              float* __restrict__ pu) {
  __shared__ __align__(16) unsigned xt[128 * 65];
  __shared__ __align__(16) unsigned pp[32 * 17];
  __shared__ __align__(16) float lred[4][16];
  const int u = (int)blockIdx.y * CH + (int)blockIdx.x;
  attn_unit(xin, xbf, qk, pl, pu, xt, pp, lred, u, FIRST, threadIdx.x);
}

__global__ __launch_bounds__(512) void k_upd(
    const float* __restrict__ pl, const float* __restrict__ pu,
    const unsigned short* __restrict__ Wv_b, const float* __restrict__ bv,
    const unsigned short* __restrict__ Wzr_b, const float* __restrict__ bzr,
    const unsigned short* __restrict__ Win_b, const float* __restrict__ bin,
    const unsigned short* __restrict__ Whn_b, const float* __restrict__ bhn,
    const unsigned short* __restrict__ W1_b, const float* __restrict__ b1,
    const unsigned short* __restrict__ W2_b, const float* __restrict__ b2,
    const float* __restrict__ gml, const float* __restrict__ bml,
    const float* __restrict__ gsl, const float* __restrict__ bsl,
    const unsigned short* __restrict__ Wqk_b, const float* __restrict__ bqk,
    float* __restrict__ slots, float* __restrict__ qk, float* __restrict__ dout) {
  __shared__ __align__(16) unsigned short cat[16 * 520];
  __shared__ __align__(16) float sp[16 * 260];
  __shared__ __align__(16) float s1[16 * 260];
  __shared__ __align__(16) unsigned short lnb[16 * 264];
  const int tid = threadIdx.x, bb = blockIdx.x;
  const int lane = tid & 63, wave = tid >> 6;
  const int m16 = lane & 15, quad = lane >> 4;
  const int row = tid >> 5, l32 = tid & 31, d0 = l32 * 8;
  const int bat = 2 * bb + (row >> 3), sl = row & 7;
  {
    float L = 0.f;
#pragma unroll
    for (int cc = 0; cc < 16; ++cc) L += pl[(bat * 16 + cc) * 8 + sl];
    float li = 1.f / L;
    float a[8] = {0.f, 0.f, 0.f, 0.f, 0.f, 0.f, 0.f, 0.f};
    for (int cc = 0; cc < 16; ++cc) {
      const float* pp_ = pu + ((size_t)(bat * 16 + cc) * 8 + sl) * 256 + d0;
      float4 v0 = *(const float4*)pp_, v1 = *(const float4*)(pp_ + 4);
      a[0] += v0.x; a[1] += v0.y; a[2] += v0.z; a[3] += v0.w;
      a[4] += v1.x; a[5] += v1.y; a[6] += v1.z; a[7] += v1.w;
    }
    uint4 o;
    o.x = bfpack2(a[0] * li, a[1] * li); o.y = bfpack2(a[2] * li, a[3] * li);
    o.z = bfpack2(a[4] * li, a[5] * li); o.w = bfpack2(a[6] * li, a[7] * li);
    *(uint4*)(cat + row * 520 + d0) = o;
    const float* sp_ = slots + (size_t)(bb * 16 + row) * 256 + d0;
    float4 h0 = *(const float4*)sp_, h1 = *(const float4*)(sp_ + 4);
    *(float4*)(sp + row * 260 + d0) = h0;
    *(float4*)(sp + row * 260 + d0 + 4) = h1;
    uint4 hb;
    hb.x = bfpack2(h0.x, h0.y); hb.y = bfpack2(h0.z, h0.w);
    hb.z = bfpack2(h1.x, h1.y); hb.w = bfpack2(h1.z, h1.w);
    *(uint4*)(cat + row * 520 + 256 + d0) = hb;
  }
  __syncthreads();
  short8 afr[16];
  load_af<8>(afr, cat, 520, m16, quad);
  f32x4 accv[2];
#pragma unroll
  for (int i = 0; i < 2; ++i) {
    int t = wave + 8 * i;
    accv[i] = gemm_tile<8>(afr, Wv_b + (size_t)(t * 16 + m16) * 256 + quad * 8,
                           bv[t * 16 + m16]);
  }
  __syncthreads();
#pragma unroll
  for (int i = 0; i < 2; ++i) {
    int t = wave + 8 * i;
#pragma unroll
    for (int r = 0; r < 4; ++r)
      cat[(quad * 4 + r) * 520 + t * 16 + m16] = bf16r(accv[i][r]);
  }
  __syncthreads();
  load_af<16>(afr, cat, 520, m16, quad);
  f32x4 rr[2], zz[2];
#pragma unroll
  for (int i = 0; i < 2; ++i) {
    int t = wave + 8 * i;
    f32x4 ar = gemm_tile<16>(afr, Wzr_b + (size_t)(t * 16 + m16) * 512 + quad * 8,
                             bzr[t * 16 + m16]);
    f32x4 az = gemm_tile<16>(afr, Wzr_b + (size_t)((t + 16) * 16 + m16) * 512 + quad * 8,
                             bzr[(t + 16) * 16 + m16]);
#pragma unroll
    for (int r = 0; r < 4; ++r) { rr[i][r] = sigm(ar[r]); zz[i][r] = sigm(az[r]); }
  }
#pragma unroll
  for (int i = 0; i < 2; ++i) {
    int t = wave + 8 * i, col = t * 16 + m16;
    f32x4 ain = gemm_tile<8>(afr, Win_b + (size_t)(t * 16 + m16) * 256 + quad * 8,
                             bin[col]);
    f32x4 ahn = gemm_tile<8>(afr + 8, Whn_b + (size_t)(t * 16 + m16) * 256 + quad * 8,
                             bhn[col]);
#pragma unroll
    for (int r = 0; r < 4; ++r) {
      int rw = quad * 4 + r;
      float nin = ain[r] + rr[i][r] * ahn[r];
      float nn = 1.f - 2.f / (__expf(2.f * nin) + 1.f);
      float hpc = sp[rw * 260 + col];
      s1[rw * 260 + col] = hpc + (1.f - zz[i][r]) * nn + zz[i][r] * hpc;
    }
  }
  __syncthreads();
  {
    const float* s1r = s1 + row * 260 + d0;
    float4 v0 = *(const float4*)s1r, v1 = *(const float4*)(s1r + 4);
    float x[8] = {v0.x, v0.y, v0.z, v0.w, v1.x, v1.y, v1.z, v1.w};
    ln_row8(x, gml, bml, d0, lnb + row * 264 + d0);
  }
  __syncthreads();
  load_af<8>(afr, lnb, 264, m16, quad);
#pragma unroll
  for (int i = 0; i < 2; ++i) {
    int t = wave + 8 * i;
    f32x4 acc = gemm_tile<8>(afr, W1_b + (size_t)(t * 16 + m16) * 256 + quad * 8,
                             b1[t * 16 + m16]);
#pragma unroll
    for (int r = 0; r < 4; ++r)
      cat[(quad * 4 + r) * 520 + t * 16 + m16] = bf16r(fmaxf(acc[r], 0.f));
  }
  __syncthreads();
  load_af<8>(afr, cat, 520, m16, quad);
#pragma unroll
  for (int i = 0; i < 2; ++i) {
    int t = wave + 8 * i;
    f32x4 acc = gemm_tile<8>(afr, W2_b + (size_t)(t * 16 + m16) * 256 + quad * 8,
                             b2[t * 16 + m16]);
#pragma unroll
    for (int r = 0; r < 4; ++r) {
      int rw = quad * 4 + r, col = t * 16 + m16;
      float v = acc[r] + s1[rw * 260 + col];
      size_t gi = (size_t)(bb * 16 + rw) * 256 + col;
      slots[gi] = v;
      if (dout) dout[gi] = v;
      sp[rw * 260 + col] = v;
    }
  }
  __syncthreads();
  {
    const float* spr = sp + row * 260 + d0;
    float4 v0 = *(const float4*)spr, v1 = *(const float4*)(spr + 4);
    float x[8] = {v0.x, v0.y, v0.z, v0.w, v1.x, v1.y, v1.z, v1.w};
    ln_row8(x, gsl, bsl, d0, lnb + row * 264 + d0);
  }
  __syncthreads();
  load_af<8>(afr, lnb, 264, m16, quad);
#pragma unroll
  for (int i = 0; i < 2; ++i) {
    int t = wave + 8 * i;
    f32x4 acc = gemm_tile<8>(afr, Wqk_b + (size_t)(t * 16 + m16) * 256 + quad * 8,
                             bqk[t * 16 + m16]);
#pragma unroll
    for (int r = 0; r < 4; ++r)
      qk[(size_t)(bb * 16 + quad * 4 + r) * 256 + t * 16 + m16] = acc[r] * 0.0625f;
  }
}

// ---------------- launch ----------------
extern "C" void kernel_launch(void* const* d_in, const int* in_sizes, int n_in,
                              void* d_out, int out_size, void* d_ws, size_t ws_size,
                              hipStream_t stream) {
  const float* inputs = (const float*)d_in[0];
  const float* noise = (const float*)d_in[1];
  const float* s_mu = (const float*)d_in[2];
  const float* s_sg = (const float*)d_in[3];
  const float* Wq = (const float*)d_in[4];
  const float* bq = (const float*)d_in[5];
  const float* Wk = (const float*)d_in[6];
  // d_in[7] = bk: unused (softmax-invariant)
  const float* Wv = (const float*)d_in[8];
  const float* bv = (const float*)d_in[9];
  const float* Wih = (const float*)d_in[10];
  const float* bih = (const float*)d_in[11];
  const float* Whh = (const float*)d_in[12];
  const float* bhh = (const float*)d_in[13];
  const float* W1 = (const float*)d_in[14];
  const float* b1 = (const float*)d_in[15];
  const float* W2 = (const float*)d_in[16];
  const float* b2 = (const float*)d_in[17];
  const float* gsl = (const float*)d_in[18];
  const float* bsl = (const float*)d_in[19];
  const float* gml = (const float*)d_in[20];
  const float* bml = (const float*)d_in[21];
  float* out = (float*)d_out;

  char* wsb = (char*)d_ws;
  unsigned* xbf = (unsigned*)wsb;  // bf16 copy of inputs: 128 MiB
  float* fp = (float*)(wsb + (size_t)Bn * Nn * Dd * 2);
  float* slots = fp; fp += Bn * Ss * Dd;
  float* qk = fp;    fp += Bn * Ss * Dd;
  float* bqk = fp;   fp += Dd;
  float* pl = fp;    fp += Bn * CH * Ss;
  float* pu = fp;    fp += Bn * CH * Ss * Dd;
  float* bzr = fp;   fp += 512;
  unsigned short* wb = (unsigned short*)fp;
  unsigned short* Wv_b = wb;  wb += 65536;
  unsigned short* Wzr_b = wb; wb += 262144;
  unsigned short* Win_b = wb; wb += 65536;
  unsigned short* Whn_b = wb; wb += 65536;
  unsigned short* W1_b = wb;  wb += 65536;
  unsigned short* W2_b = wb;  wb += 65536;
  unsigned short* Wqk_b = wb; wb += 65536;
  (void)in_sizes; (void)n_in; (void)out_size; (void)ws_size;

  MegaArgs ma;
  ma.inputs = inputs; ma.noise = noise; ma.s_mu = s_mu; ma.s_sg = s_sg;
  ma.Wq = Wq; ma.bq = bq; ma.Wk = Wk; ma.Wv = Wv; ma.bv = bv;
  ma.Wih = Wih; ma.bih = bih; ma.Whh = Whh; ma.bhh = bhh;
  ma.W1 = W1; ma.b1 = b1; ma.W2 = W2; ma.b2 = b2;
  ma.gsl = gsl; ma.bsl = bsl; ma.gml = gml; ma.bml = bml;
  ma.xbf = xbf; ma.slots = slots; ma.qk = qk; ma.bqk = bqk;
  ma.pl = pl; ma.pu = pu; ma.bzr = bzr;
  ma.Wv_b = Wv_b; ma.Wzr_b = Wzr_b; ma.Win_b = Win_b; ma.Whn_b = Whn_b;
  ma.W1_b = W1_b; ma.W2_b = W2_b; ma.Wqk_b = Wqk_b;
  ma.out = out;

  int maxB = 0;
  hipError_t oerr = hipOccupancyMaxActiveBlocksPerMultiprocessor(
      &maxB, (const void*)k_mega, 256, 0);
  int gridN = (oerr == hipSuccess && maxB > 0) ? maxB * 256 : 0;
  if (gridN > 1024) gridN = 1024;
  hipError_t err = hipErrorUnknown;
  if (gridN >= 256) {
    void* kargs[] = {(void*)&ma};
    err = hipLaunchCooperativeKernel((const void*)k_mega, dim3(gridN), dim3(256),
                                     kargs, 0, stream);
  }
  if (err != hipSuccess) {
    (void)hipGetLastError();  // clear sticky error; fall back to benched R7 path
    k_wqk<<<dim3(257), dim3(256), 0, stream>>>(Wq, Wk, bq, Wqk_b, bqk);
    k_conv<<<dim3(1154), dim3(256), 0, stream>>>(
        Wv, Wih, Whh, W1, W2, bih, bhh, (unsigned*)Wv_b, (unsigned*)Wzr_b,
        (unsigned*)Win_b, (unsigned*)Whn_b, (unsigned*)W1_b, (unsigned*)W2_b, bzr);
    k_qk0<<<dim3(32), dim3(512), 0, stream>>>(noise, s_mu, s_sg, gsl, bsl, Wqk_b, bqk,
                                              slots, qk);
    for (int it = 0; it < 3; ++it) {
      if (it == 0)
        k_attn<true><<<dim3(CH, Bn), dim3(256), 0, stream>>>(inputs, xbf, qk, pl, pu);
      else
        k_attn<false><<<dim3(CH, Bn), dim3(256), 0, stream>>>(nullptr, xbf, qk, pl, pu);
      k_upd<<<dim3(32), dim3(512), 0, stream>>>(
          pl, pu, Wv_b, bv, Wzr_b, bzr, Win_b, bih + 512, Whn_b, bhh + 512, W1_b, b1,
          W2_b, b2, gml, bml, gsl, bsl, Wqk_b, bqk, slots, qk, (it == 2) ? out : nullptr);
    }
  }
}